// Round 8
// baseline (686.979 us; speedup 1.0000x reference)
//
#include <hip/hip_runtime.h>
#include <hip/hip_bf16.h>
#include <math.h>

#define NB 32
#define LSEQ 2048
#define DIN 64
#define NH 256
#define NN 32
#define NST 8     // states per thread (lane-quad split)
#define NLAY 2
#define NCH 32
#define TCH 64    // LSEQ/NCH
#define LTILE 64
#define ML1 350
#define ML2 400
#define MOUT 1024
#define LN_EPS 1e-5f

typedef short short8 __attribute__((ext_vector_type(8)));
typedef float f32x4 __attribute__((ext_vector_type(4)));
typedef float f32x2 __attribute__((ext_vector_type(2)));

// Complex recurrence via packed f32 (VOP3P), 2 instructions per state-step:
//   R = pk_fma(E, S, U)  with E lo-broadcast, U=(u,0):
//       R.lo = er*sr + u ; R.hi = er*si
//   S = pk_fma(E, S, R)  with E hi for both halves, S swapped, neg_lo on E:
//       S.lo = -ei*si + R.lo = er*sr - ei*si + u
//       S.hi =  ei*sr + R.hi = ei*sr + er*si
#define PK_STEP(E, S, U)                                                        \
    {                                                                           \
        f32x2 R_;                                                               \
        asm("v_pk_fma_f32 %0, %1, %2, %3 op_sel:[0,0,0] op_sel_hi:[0,1,1]"      \
            : "=v"(R_) : "v"(E), "v"(S), "v"(U));                               \
        asm("v_pk_fma_f32 %0, %1, %0, %2 op_sel:[1,1,0] op_sel_hi:[1,0,1] neg_lo:[1,0,0]" \
            : "+v"(S) : "v"(E), "v"(R_));                                       \
    }
// A += (cr*sr, -ci*si):
#define PK_ACC(C, S, A)                                                         \
    asm("v_pk_fma_f32 %0, %1, %2, %0 neg_hi:[1,0,0]" : "+v"(A) : "v"(C), "v"(S));

// ---------------- coefficient prep ----------------
__global__ void s4w_coef(const float* __restrict__ log_dt,
                         const float* __restrict__ C_re, const float* __restrict__ C_im,
                         const float* __restrict__ log_A_real, const float* __restrict__ A_imag,
                         float* __restrict__ ctr, float* __restrict__ cti,
                         float* __restrict__ er_, float* __restrict__ ei_,
                         float* __restrict__ pr_, float* __restrict__ pi_) {
    int idx = blockIdx.x * 256 + threadIdx.x;
    if (idx >= NLAY * NH * NN) return;
    int h = (idx / NN) % NH;
    int l = idx / (NN * NH);
    float dt = expf(log_dt[l * NH + h]);
    float ar = -expf(log_A_real[idx]);
    float ai = A_imag[idx];
    float dre = ar * dt, dim = ai * dt;
    float ex = expf(dre);
    float er = ex * cosf(dim);
    float ei = ex * sinf(dim);
    float den = ar * ar + ai * ai;
    float qr = ((er - 1.0f) * ar + ei * ai) / den;
    float qi = (ei * ar - (er - 1.0f) * ai) / den;
    float cr = C_re[idx], ci = C_im[idx];
    ctr[idx] = 2.0f * (cr * qr - ci * qi);
    cti[idx] = 2.0f * (cr * qi + ci * qr);
    er_[idx] = er; ei_[idx] = ei;
    double exT = exp((double)dre * (double)TCH);
    double ang = (double)dim * (double)TCH;
    pr_[idx] = (float)(exT * cos(ang));
    pi_[idx] = (float)(exT * sin(ang));
}

// ---------------- weight prep: out_w -> bf16 ----------------
__global__ void s4w_wprep(const float* __restrict__ ow, __hip_bfloat16* __restrict__ wbf) {
    int idx = blockIdx.x * 256 + threadIdx.x;
    wbf[idx] = __float2bfloat16(ow[idx]);
}

// ---------------- encoder ----------------
__global__ void __launch_bounds__(256, 2)
s4w_enc(const float* __restrict__ x, const float* __restrict__ w,
        const float* __restrict__ bias, float* __restrict__ hbuf) {
    int blk = blockIdx.x;
    int b = blk / (LSEQ / 16);
    int l0 = (blk % (LSEQ / 16)) * 16;
    int t = threadIdx.x;
    __shared__ float xs[16][DIN];
    ((float4*)&xs[0][0])[t] = ((const float4*)(x + ((size_t)b * LSEQ + l0) * DIN))[t];
    float wr[DIN];
    const float4* wp4 = (const float4*)(w + (size_t)t * DIN);
#pragma unroll
    for (int i = 0; i < DIN / 4; i++) {
        float4 v = wp4[i];
        wr[4 * i] = v.x; wr[4 * i + 1] = v.y; wr[4 * i + 2] = v.z; wr[4 * i + 3] = v.w;
    }
    float bz = bias[t];
    __syncthreads();
#pragma unroll 4
    for (int l = 0; l < 16; l++) {
        float acc = bz;
#pragma unroll
        for (int i = 0; i < DIN; i++) acc = fmaf(wr[i], xs[l][i], acc);
        hbuf[((size_t)b * LSEQ + l0 + l) * NH + t] = acc;
    }
}

// ---------------- conv phase A (packed f32, lane-quad split: 8 states/thread) ----------------
// 256 threads = 64 h x 4 quarters; grid (NB, NCH, 4), z*64 = h offset.
__global__ void __launch_bounds__(256, 2)
s4w_convA(const float* __restrict__ hbuf,
          const float* __restrict__ er_, const float* __restrict__ ei_,
          float2* __restrict__ states, int layer) {
    int b = blockIdx.x, c = blockIdx.y;
    int t = threadIdx.x;
    int h = blockIdx.z * 64 + (t >> 2), q = t & 3;
    f32x2 E[NST], S[NST];
    const float* eb0 = er_ + (size_t)(layer * NH + h) * NN + q * NST;
    const float* eb1 = ei_ + (size_t)(layer * NH + h) * NN + q * NST;
#pragma unroll
    for (int n = 0; n < NST; n++) {
        E[n].x = eb0[n]; E[n].y = eb1[n];
        S[n].x = 0.f; S[n].y = 0.f;
    }
    const float* up = hbuf + ((size_t)b * LSEQ + c * TCH) * NH + h;
#pragma unroll 2
    for (int j = 0; j < TCH; j++) {
        f32x2 U;
        U.x = up[(size_t)j * NH];
        U.y = 0.f;
#pragma unroll
        for (int n = 0; n < NST; n++) PK_STEP(E[n], S[n], U)
    }
    float2* sp = states + ((size_t)(b * NCH + c) * NH + h) * NN + q * NST;
#pragma unroll
    for (int n = 0; n < NST; n++) sp[n] = make_float2(S[n].x, S[n].y);
}

// ---------------- conv phase B: inter-chunk scan ----------------
__global__ void s4w_scan(float2* __restrict__ states,
                         const float* __restrict__ pr_, const float* __restrict__ pi_, int layer) {
    int idx = blockIdx.x * 256 + threadIdx.x;
    int b = idx / (NH * NN);
    int hn = idx % (NH * NN);
    float pr = pr_[(size_t)layer * NH * NN + hn];
    float pi = pi_[(size_t)layer * NH * NN + hn];
    float sr = 0.f, si = 0.f;
    float2* sp = states + (size_t)b * NCH * NH * NN + hn;
    for (int c = 0; c < NCH; c++) {
        float2 e = sp[(size_t)c * NH * NN];
        sp[(size_t)c * NH * NN] = make_float2(sr, si);
        float nsr = pr * sr - pi * si + e.x;
        float nsi = pr * si + pi * sr + e.y;
        sr = nsr; si = nsi;
    }
}

// ---------------- conv phase C (packed f32, lane-quad split): replay + Dp + GELU -> bf16 ----------------
__global__ void __launch_bounds__(256, 2)
s4w_convC(const float* __restrict__ hbuf, __hip_bfloat16* __restrict__ ybf,
          const float2* __restrict__ states,
          const float* __restrict__ er_, const float* __restrict__ ei_,
          const float* __restrict__ ctr_, const float* __restrict__ cti_,
          const float* __restrict__ Dp, int layer) {
    int b = blockIdx.x, c = blockIdx.y;
    int t = threadIdx.x;
    int h = blockIdx.z * 64 + (t >> 2), q = t & 3;
    f32x2 E[NST], S[NST], C[NST];
    size_t cbase = (size_t)(layer * NH + h) * NN + q * NST;
    const float2* sp = states + ((size_t)(b * NCH + c) * NH + h) * NN + q * NST;
#pragma unroll
    for (int n = 0; n < NST; n++) {
        E[n].x = er_[cbase + n]; E[n].y = ei_[cbase + n];
        C[n].x = ctr_[cbase + n]; C[n].y = cti_[cbase + n];
        float2 s0 = sp[n];
        S[n].x = s0.x; S[n].y = s0.y;
    }
    float dp = Dp[layer * NH + h];
    const float* up = hbuf + ((size_t)b * LSEQ + c * TCH) * NH + h;
    __hip_bfloat16* yp = ybf + ((size_t)b * LSEQ + c * TCH) * NH + h;
#pragma unroll 2
    for (int j = 0; j < TCH; j++) {
        float u = up[(size_t)j * NH];
        f32x2 U; U.x = u; U.y = 0.f;
        f32x2 A0; A0.x = 0.f; A0.y = 0.f;
        f32x2 A1; A1.x = 0.f; A1.y = 0.f;
#pragma unroll
        for (int n = 0; n < NST; n++) {
            PK_STEP(E[n], S[n], U)
            if (n & 1) { PK_ACC(C[n], S[n], A1) }
            else       { PK_ACC(C[n], S[n], A0) }
        }
        float part = (A0.x + A0.y) + (A1.x + A1.y);
        part += __shfl_xor(part, 1, 64);   // combine within lane-quad
        part += __shfl_xor(part, 2, 64);
        float yv = fmaf(u, dp, part);
        float g = 0.5f * yv * (1.0f + erff(yv * 0.70710678118f));
        if (q == 0) yp[(size_t)j * NH] = __float2bfloat16(g);
    }
}

// ---------------- proj: bf16 MFMA GEMM + GLU + residual + channel-LN ----------------
__global__ void __launch_bounds__(256, 2)
s4w_proj_mfma(const __hip_bfloat16* __restrict__ ybf, float* __restrict__ hbuf,
              const __hip_bfloat16* __restrict__ wbf, const float* __restrict__ ob,
              const float* __restrict__ lnw, const float* __restrict__ lnb, int layer) {
    int b = blockIdx.x;
    int n0 = blockIdx.y * LTILE;
    int t = threadIdx.x;
    int wave = t >> 6, lane = t & 63;
    int lm = lane & 15, kg = lane >> 4;

    __shared__ float glu[LTILE][NH + 1];
    __shared__ float ps[256], pq[256];
    __shared__ float mean_s[LTILE], rstd_s[LTILE];

    f32x4 acc[8][4];
#pragma unroll
    for (int i = 0; i < 8; i++)
#pragma unroll
        for (int j = 0; j < 4; j++) acc[i][j] = (f32x4){0.f, 0.f, 0.f, 0.f};

    const short* wp = (const short*)(wbf) + (size_t)layer * 512 * NH;
    const short* yp = (const short*)(ybf) + ((size_t)b * LSEQ + n0) * NH;

    const short8* aptr[8];
#pragma unroll
    for (int mi = 0; mi < 8; mi++) {
        int o = (mi < 4 ? wave * 64 + mi * 16 : 256 + wave * 64 + (mi - 4) * 16) + lm;
        aptr[mi] = (const short8*)(wp + (size_t)o * NH + kg * 8);
    }
    const short8* bptr[4];
#pragma unroll
    for (int ni = 0; ni < 4; ni++) {
        int l = ni * 16 + lm;
        bptr[ni] = (const short8*)(yp + (size_t)l * NH + kg * 8);
    }

#pragma unroll
    for (int ks = 0; ks < 8; ks++) {
        short8 bv[4], av[8];
#pragma unroll
        for (int ni = 0; ni < 4; ni++) bv[ni] = bptr[ni][ks * 4];
#pragma unroll
        for (int mi = 0; mi < 8; mi++) av[mi] = aptr[mi][ks * 4];
#pragma unroll
        for (int mi = 0; mi < 8; mi++)
#pragma unroll
            for (int ni = 0; ni < 4; ni++)
                acc[mi][ni] = __builtin_amdgcn_mfma_f32_16x16x32_bf16(av[mi], bv[ni], acc[mi][ni], 0, 0, 0);
    }

    float oba[4][4], obg[4][4];
#pragma unroll
    for (int mi = 0; mi < 4; mi++)
#pragma unroll
        for (int j = 0; j < 4; j++) {
            int o = wave * 64 + mi * 16 + kg * 4 + j;
            oba[mi][j] = ob[layer * 2 * NH + o];
            obg[mi][j] = ob[layer * 2 * NH + NH + o];
        }
#pragma unroll
    for (int mi = 0; mi < 4; mi++)
#pragma unroll
        for (int ni = 0; ni < 4; ni++)
#pragma unroll
            for (int j = 0; j < 4; j++) {
                float a = acc[mi][ni][j] + oba[mi][j];
                float g = acc[mi + 4][ni][j] + obg[mi][j];
                float v = a * (1.0f / (1.0f + expf(-g)));
                int o = wave * 64 + mi * 16 + kg * 4 + j;
                int l = ni * 16 + lm;
                glu[l][o] = v;
            }
    __syncthreads();

    const size_t hbase = ((size_t)b * LSEQ + n0) * NH;
    for (int l = 0; l < LTILE; l++)
        glu[l][t] += hbuf[hbase + (size_t)l * NH + t];
    __syncthreads();

    {
        int l = t & 63, seg = t >> 6;
        float s = 0.f, q = 0.f;
#pragma unroll
        for (int i = 0; i < 64; i++) {
            float v = glu[l][seg * 64 + i];
            s += v; q = fmaf(v, v, q);
        }
        ps[t] = s; pq[t] = q;
    }
    __syncthreads();
    if (t < 64) {
        float S = ps[t] + ps[64 + t] + ps[128 + t] + ps[192 + t];
        float Q = pq[t] + pq[64 + t] + pq[128 + t] + pq[192 + t];
        float m = S * (1.0f / NH);
        float v = Q * (1.0f / NH) - m * m;
        mean_s[t] = m; rstd_s[t] = rsqrtf(v + LN_EPS);
    }
    __syncthreads();

    float lw = lnw[layer * NH + t], lb = lnb[layer * NH + t];
    for (int l = 0; l < LTILE; l++) {
        float v = (glu[l][t] - mean_s[l]) * rstd_s[l] * lw + lb;
        hbuf[hbase + (size_t)l * NH + t] = v;
    }
}

// ---------------- head MLP: one wave per output element, lane-split K ----------------
__global__ void __launch_bounds__(256, 4)
s4w_mlp_wave(const float* __restrict__ in, size_t in_bstride,
             const float* __restrict__ w, const float* __restrict__ bias,
             float* __restrict__ out, int K, int N, int do_relu) {
    int wid = (blockIdx.x * 256 + threadIdx.x) >> 6;
    int lane = threadIdx.x & 63;
    if (wid >= NB * N) return;
    int b = wid / N, o = wid % N;
    const float* ip = in + (size_t)b * in_bstride;
    const float* wp = w + (size_t)o * K;
    float acc = 0.f;
    for (int k = lane; k < K; k += 64) acc = fmaf(wp[k], ip[k], acc);
#pragma unroll
    for (int off = 32; off > 0; off >>= 1) acc += __shfl_xor(acc, off, 64);
    if (lane == 0) {
        float v = acc + bias[o];
        out[(size_t)b * N + o] = do_relu ? fmaxf(v, 0.f) : v;
    }
}

extern "C" void kernel_launch(void* const* d_in, const int* in_sizes, int n_in,
                              void* d_out, int out_size, void* d_ws, size_t ws_size,
                              hipStream_t stream) {
    const float* x          = (const float*)d_in[0];
    const float* enc_w      = (const float*)d_in[1];
    const float* enc_b      = (const float*)d_in[2];
    const float* log_dt     = (const float*)d_in[3];
    const float* C_re       = (const float*)d_in[4];
    const float* C_im       = (const float*)d_in[5];
    const float* log_A_real = (const float*)d_in[6];
    const float* A_imag     = (const float*)d_in[7];
    const float* Dp         = (const float*)d_in[8];
    const float* out_w      = (const float*)d_in[9];
    const float* out_b      = (const float*)d_in[10];
    const float* ln_w       = (const float*)d_in[11];
    const float* ln_b       = (const float*)d_in[12];
    const float* lin1_w     = (const float*)d_in[13];
    const float* lin1_b     = (const float*)d_in[14];
    const float* lin2_w     = (const float*)d_in[15];
    const float* lin2_b     = (const float*)d_in[16];
    const float* lin3_w     = (const float*)d_in[17];
    const float* lin3_b     = (const float*)d_in[18];
    float* outp = (float*)d_out;

    float* ws = (float*)d_ws;
    size_t off = 0;
    float* hbuf   = ws + off; off += (size_t)NB * LSEQ * NH;
    __hip_bfloat16* ybf = (__hip_bfloat16*)(ws + off); off += (size_t)NB * LSEQ * NH / 2;
    __hip_bfloat16* wbf = (__hip_bfloat16*)(ws + off); off += (size_t)NLAY * 2 * NH * NH / 2;
    float2* states = (float2*)(ws + off); off += (size_t)NB * NCH * NH * NN * 2;
    float* ctr    = ws + off; off += NLAY * NH * NN;
    float* cti    = ws + off; off += NLAY * NH * NN;
    float* er_    = ws + off; off += NLAY * NH * NN;
    float* ei_    = ws + off; off += NLAY * NH * NN;
    float* pr_    = ws + off; off += NLAY * NH * NN;
    float* pi_    = ws + off; off += NLAY * NH * NN;
    float* t1     = ws + off; off += NB * ML1;
    float* t2     = ws + off; off += NB * ML2;

    s4w_coef<<<(NLAY * NH * NN + 255) / 256, 256, 0, stream>>>(
        log_dt, C_re, C_im, log_A_real, A_imag, ctr, cti, er_, ei_, pr_, pi_);

    s4w_wprep<<<(NLAY * 2 * NH * NH) / 256, 256, 0, stream>>>(out_w, wbf);

    s4w_enc<<<NB * (LSEQ / 16), 256, 0, stream>>>(x, enc_w, enc_b, hbuf);

    for (int layer = 0; layer < NLAY; layer++) {
        s4w_convA<<<dim3(NB, NCH, 4), 256, 0, stream>>>(hbuf, er_, ei_, states, layer);
        s4w_scan<<<(NB * NH * NN) / 256, 256, 0, stream>>>(states, pr_, pi_, layer);
        s4w_convC<<<dim3(NB, NCH, 4), 256, 0, stream>>>(hbuf, ybf, states, er_, ei_, ctr, cti, Dp, layer);
        s4w_proj_mfma<<<dim3(NB, LSEQ / LTILE), 256, 0, stream>>>(ybf, hbuf, wbf, out_b, ln_w, ln_b, layer);
    }

    s4w_mlp_wave<<<(NB * ML1 + 3) / 4, 256, 0, stream>>>(
        hbuf + (size_t)(LSEQ - 1) * NH, (size_t)LSEQ * NH, lin1_w, lin1_b, t1, NH, ML1, 1);
    s4w_mlp_wave<<<(NB * ML2 + 3) / 4, 256, 0, stream>>>(
        t1, ML1, lin2_w, lin2_b, t2, ML1, ML2, 1);
    s4w_mlp_wave<<<(NB * MOUT + 3) / 4, 256, 0, stream>>>(
        t2, ML2, lin3_w, lin3_b, outp, ML2, MOUT, 0);
}

// Round 9
// 659.139 us; speedup vs baseline: 1.0422x; 1.0422x over previous
//
#include <hip/hip_runtime.h>
#include <hip/hip_bf16.h>
#include <math.h>

#define NB 32
#define LSEQ 2048
#define DIN 64
#define NH 256
#define NN 32
#define NLAY 2
#define NCH 32
#define TCH 64    // LSEQ/NCH
#define LTILE 64
#define ML1 350
#define ML2 400
#define MOUT 1024
#define LN_EPS 1e-5f

typedef short short8 __attribute__((ext_vector_type(8)));
typedef float f32x4 __attribute__((ext_vector_type(4)));
typedef float f32x2 __attribute__((ext_vector_type(2)));

// Complex recurrence via packed f32 (VOP3P), 2 instructions per state-step:
//   R = pk_fma(E, S, U)  with E lo-broadcast, U=(u,0):
//       R.lo = er*sr + u ; R.hi = er*si
//   S = pk_fma(E, S, R)  with E hi for both halves, S swapped, neg_lo on E:
//       S.lo = -ei*si + R.lo = er*sr - ei*si + u
//       S.hi =  ei*sr + R.hi = ei*sr + er*si
#define PK_STEP(E, S, U)                                                        \
    {                                                                           \
        f32x2 R_;                                                               \
        asm("v_pk_fma_f32 %0, %1, %2, %3 op_sel:[0,0,0] op_sel_hi:[0,1,1]"      \
            : "=v"(R_) : "v"(E), "v"(S), "v"(U));                               \
        asm("v_pk_fma_f32 %0, %1, %0, %2 op_sel:[1,1,0] op_sel_hi:[1,0,1] neg_lo:[1,0,0]" \
            : "+v"(S) : "v"(E), "v"(R_));                                       \
    }
// A += (cr*sr, -ci*si):
#define PK_ACC(C, S, A)                                                         \
    asm("v_pk_fma_f32 %0, %1, %2, %0 neg_hi:[1,0,0]" : "+v"(A) : "v"(C), "v"(S));

// Pin a value into an arch VGPR: asm-defined values cannot be rematerialized
// by re-running the original load, so the allocator must keep them resident.
#define PIN(X) asm("" : "+v"(X));

// ---------------- coefficient prep ----------------
__global__ void s4w_coef(const float* __restrict__ log_dt,
                         const float* __restrict__ C_re, const float* __restrict__ C_im,
                         const float* __restrict__ log_A_real, const float* __restrict__ A_imag,
                         float* __restrict__ ctr, float* __restrict__ cti,
                         float* __restrict__ er_, float* __restrict__ ei_,
                         float* __restrict__ pr_, float* __restrict__ pi_) {
    int idx = blockIdx.x * 256 + threadIdx.x;
    if (idx >= NLAY * NH * NN) return;
    int h = (idx / NN) % NH;
    int l = idx / (NN * NH);
    float dt = expf(log_dt[l * NH + h]);
    float ar = -expf(log_A_real[idx]);
    float ai = A_imag[idx];
    float dre = ar * dt, dim = ai * dt;
    float ex = expf(dre);
    float er = ex * cosf(dim);
    float ei = ex * sinf(dim);
    float den = ar * ar + ai * ai;
    float qr = ((er - 1.0f) * ar + ei * ai) / den;
    float qi = (ei * ar - (er - 1.0f) * ai) / den;
    float cr = C_re[idx], ci = C_im[idx];
    ctr[idx] = 2.0f * (cr * qr - ci * qi);
    cti[idx] = 2.0f * (cr * qi + ci * qr);
    er_[idx] = er; ei_[idx] = ei;
    double exT = exp((double)dre * (double)TCH);
    double ang = (double)dim * (double)TCH;
    pr_[idx] = (float)(exT * cos(ang));
    pi_[idx] = (float)(exT * sin(ang));
}

// ---------------- weight prep: out_w -> bf16 ----------------
__global__ void s4w_wprep(const float* __restrict__ ow, __hip_bfloat16* __restrict__ wbf) {
    int idx = blockIdx.x * 256 + threadIdx.x;
    wbf[idx] = __float2bfloat16(ow[idx]);
}

// ---------------- encoder ----------------
__global__ void __launch_bounds__(256, 2)
s4w_enc(const float* __restrict__ x, const float* __restrict__ w,
        const float* __restrict__ bias, float* __restrict__ hbuf) {
    int blk = blockIdx.x;
    int b = blk / (LSEQ / 16);
    int l0 = (blk % (LSEQ / 16)) * 16;
    int t = threadIdx.x;
    __shared__ float xs[16][DIN];
    ((float4*)&xs[0][0])[t] = ((const float4*)(x + ((size_t)b * LSEQ + l0) * DIN))[t];
    float wr[DIN];
    const float4* wp4 = (const float4*)(w + (size_t)t * DIN);
#pragma unroll
    for (int i = 0; i < DIN / 4; i++) {
        float4 v = wp4[i];
        wr[4 * i] = v.x; wr[4 * i + 1] = v.y; wr[4 * i + 2] = v.z; wr[4 * i + 3] = v.w;
    }
    float bz = bias[t];
    __syncthreads();
#pragma unroll 4
    for (int l = 0; l < 16; l++) {
        float acc = bz;
#pragma unroll
        for (int i = 0; i < DIN; i++) acc = fmaf(wr[i], xs[l][i], acc);
        hbuf[((size_t)b * LSEQ + l0 + l) * NH + t] = acc;
    }
}

// ---------------- conv phase A (packed f32, monolithic 32 states, pinned coefs) ----------------
__global__ void __launch_bounds__(256, 1)
s4w_convA(const float* __restrict__ hbuf,
          const float* __restrict__ er_, const float* __restrict__ ei_,
          float2* __restrict__ states, int layer) {
    int b = blockIdx.x, c = blockIdx.y, h = threadIdx.x;
    f32x2 E[NN], S[NN];
    const float* eb0 = er_ + (size_t)(layer * NH + h) * NN;
    const float* eb1 = ei_ + (size_t)(layer * NH + h) * NN;
#pragma unroll
    for (int n = 0; n < NN; n++) {
        E[n].x = eb0[n]; E[n].y = eb1[n];
        S[n].x = 0.f; S[n].y = 0.f;
    }
#pragma unroll
    for (int n = 0; n < NN; n++) { PIN(E[n]) }
    const float* up = hbuf + ((size_t)b * LSEQ + c * TCH) * NH + h;
#pragma unroll 2
    for (int j = 0; j < TCH; j++) {
        f32x2 U;
        U.x = up[(size_t)j * NH];
        U.y = 0.f;
#pragma unroll
        for (int n = 0; n < NN; n++) PK_STEP(E[n], S[n], U)
    }
    float2* sp = states + ((size_t)(b * NCH + c) * NH + h) * NN;
#pragma unroll
    for (int n = 0; n < NN; n++) sp[n] = make_float2(S[n].x, S[n].y);
}

// ---------------- conv phase B: inter-chunk scan ----------------
__global__ void s4w_scan(float2* __restrict__ states,
                         const float* __restrict__ pr_, const float* __restrict__ pi_, int layer) {
    int idx = blockIdx.x * 256 + threadIdx.x;
    int b = idx / (NH * NN);
    int hn = idx % (NH * NN);
    float pr = pr_[(size_t)layer * NH * NN + hn];
    float pi = pi_[(size_t)layer * NH * NN + hn];
    float sr = 0.f, si = 0.f;
    float2* sp = states + (size_t)b * NCH * NH * NN + hn;
    for (int c = 0; c < NCH; c++) {
        float2 e = sp[(size_t)c * NH * NN];
        sp[(size_t)c * NH * NN] = make_float2(sr, si);
        float nsr = pr * sr - pi * si + e.x;
        float nsi = pr * si + pi * sr + e.y;
        sr = nsr; si = nsi;
    }
}

// ---------------- conv phase C (packed f32, monolithic, pinned coefs): replay + Dp + GELU -> bf16 ----------------
__global__ void __launch_bounds__(256, 1)
s4w_convC(const float* __restrict__ hbuf, __hip_bfloat16* __restrict__ ybf,
          const float2* __restrict__ states,
          const float* __restrict__ er_, const float* __restrict__ ei_,
          const float* __restrict__ ctr_, const float* __restrict__ cti_,
          const float* __restrict__ Dp, int layer) {
    int b = blockIdx.x, c = blockIdx.y, h = threadIdx.x;
    f32x2 E[NN], S[NN], C[NN];
    size_t cbase = (size_t)(layer * NH + h) * NN;
    const float2* sp = states + ((size_t)(b * NCH + c) * NH + h) * NN;
#pragma unroll
    for (int n = 0; n < NN; n++) {
        E[n].x = er_[cbase + n]; E[n].y = ei_[cbase + n];
        C[n].x = ctr_[cbase + n]; C[n].y = cti_[cbase + n];
        float2 s0 = sp[n];
        S[n].x = s0.x; S[n].y = s0.y;
    }
#pragma unroll
    for (int n = 0; n < NN; n++) { PIN(E[n]) PIN(C[n]) }
    float dp = Dp[layer * NH + h];
    const float* up = hbuf + ((size_t)b * LSEQ + c * TCH) * NH + h;
    __hip_bfloat16* yp = ybf + ((size_t)b * LSEQ + c * TCH) * NH + h;
#pragma unroll 2
    for (int j = 0; j < TCH; j++) {
        float u = up[(size_t)j * NH];
        f32x2 U; U.x = u; U.y = 0.f;
        f32x2 A0; A0.x = 0.f; A0.y = 0.f;
        f32x2 A1; A1.x = 0.f; A1.y = 0.f;
#pragma unroll
        for (int n = 0; n < NN; n++) {
            PK_STEP(E[n], S[n], U)
            if (n & 1) { PK_ACC(C[n], S[n], A1) }
            else       { PK_ACC(C[n], S[n], A0) }
        }
        float yv = (A0.x + A0.y) + (A1.x + A1.y);
        yv = fmaf(u, dp, yv);
        float g = 0.5f * yv * (1.0f + erff(yv * 0.70710678118f));
        yp[(size_t)j * NH] = __float2bfloat16(g);
    }
}

// ---------------- proj: bf16 MFMA GEMM + GLU + residual + channel-LN ----------------
__global__ void __launch_bounds__(256, 2)
s4w_proj_mfma(const __hip_bfloat16* __restrict__ ybf, float* __restrict__ hbuf,
              const __hip_bfloat16* __restrict__ wbf, const float* __restrict__ ob,
              const float* __restrict__ lnw, const float* __restrict__ lnb, int layer) {
    int b = blockIdx.x;
    int n0 = blockIdx.y * LTILE;
    int t = threadIdx.x;
    int wave = t >> 6, lane = t & 63;
    int lm = lane & 15, kg = lane >> 4;

    __shared__ float glu[LTILE][NH + 1];
    __shared__ float ps[256], pq[256];
    __shared__ float mean_s[LTILE], rstd_s[LTILE];

    f32x4 acc[8][4];
#pragma unroll
    for (int i = 0; i < 8; i++)
#pragma unroll
        for (int j = 0; j < 4; j++) acc[i][j] = (f32x4){0.f, 0.f, 0.f, 0.f};

    const short* wp = (const short*)(wbf) + (size_t)layer * 512 * NH;
    const short* yp = (const short*)(ybf) + ((size_t)b * LSEQ + n0) * NH;

    const short8* aptr[8];
#pragma unroll
    for (int mi = 0; mi < 8; mi++) {
        int o = (mi < 4 ? wave * 64 + mi * 16 : 256 + wave * 64 + (mi - 4) * 16) + lm;
        aptr[mi] = (const short8*)(wp + (size_t)o * NH + kg * 8);
    }
    const short8* bptr[4];
#pragma unroll
    for (int ni = 0; ni < 4; ni++) {
        int l = ni * 16 + lm;
        bptr[ni] = (const short8*)(yp + (size_t)l * NH + kg * 8);
    }

#pragma unroll
    for (int ks = 0; ks < 8; ks++) {
        short8 bv[4], av[8];
#pragma unroll
        for (int ni = 0; ni < 4; ni++) bv[ni] = bptr[ni][ks * 4];
#pragma unroll
        for (int mi = 0; mi < 8; mi++) av[mi] = aptr[mi][ks * 4];
#pragma unroll
        for (int mi = 0; mi < 8; mi++)
#pragma unroll
            for (int ni = 0; ni < 4; ni++)
                acc[mi][ni] = __builtin_amdgcn_mfma_f32_16x16x32_bf16(av[mi], bv[ni], acc[mi][ni], 0, 0, 0);
    }

    float oba[4][4], obg[4][4];
#pragma unroll
    for (int mi = 0; mi < 4; mi++)
#pragma unroll
        for (int j = 0; j < 4; j++) {
            int o = wave * 64 + mi * 16 + kg * 4 + j;
            oba[mi][j] = ob[layer * 2 * NH + o];
            obg[mi][j] = ob[layer * 2 * NH + NH + o];
        }
#pragma unroll
    for (int mi = 0; mi < 4; mi++)
#pragma unroll
        for (int ni = 0; ni < 4; ni++)
#pragma unroll
            for (int j = 0; j < 4; j++) {
                float a = acc[mi][ni][j] + oba[mi][j];
                float g = acc[mi + 4][ni][j] + obg[mi][j];
                float v = a * (1.0f / (1.0f + expf(-g)));
                int o = wave * 64 + mi * 16 + kg * 4 + j;
                int l = ni * 16 + lm;
                glu[l][o] = v;
            }
    __syncthreads();

    const size_t hbase = ((size_t)b * LSEQ + n0) * NH;
    for (int l = 0; l < LTILE; l++)
        glu[l][t] += hbuf[hbase + (size_t)l * NH + t];
    __syncthreads();

    {
        int l = t & 63, seg = t >> 6;
        float s = 0.f, q = 0.f;
#pragma unroll
        for (int i = 0; i < 64; i++) {
            float v = glu[l][seg * 64 + i];
            s += v; q = fmaf(v, v, q);
        }
        ps[t] = s; pq[t] = q;
    }
    __syncthreads();
    if (t < 64) {
        float S = ps[t] + ps[64 + t] + ps[128 + t] + ps[192 + t];
        float Q = pq[t] + pq[64 + t] + pq[128 + t] + pq[192 + t];
        float m = S * (1.0f / NH);
        float v = Q * (1.0f / NH) - m * m;
        mean_s[t] = m; rstd_s[t] = rsqrtf(v + LN_EPS);
    }
    __syncthreads();

    float lw = lnw[layer * NH + t], lb = lnb[layer * NH + t];
    for (int l = 0; l < LTILE; l++) {
        float v = (glu[l][t] - mean_s[l]) * rstd_s[l] * lw + lb;
        hbuf[hbase + (size_t)l * NH + t] = v;
    }
}

// ---------------- head MLP: one wave per output element, lane-split K ----------------
__global__ void __launch_bounds__(256, 4)
s4w_mlp_wave(const float* __restrict__ in, size_t in_bstride,
             const float* __restrict__ w, const float* __restrict__ bias,
             float* __restrict__ out, int K, int N, int do_relu) {
    int wid = (blockIdx.x * 256 + threadIdx.x) >> 6;
    int lane = threadIdx.x & 63;
    if (wid >= NB * N) return;
    int b = wid / N, o = wid % N;
    const float* ip = in + (size_t)b * in_bstride;
    const float* wp = w + (size_t)o * K;
    float acc = 0.f;
    for (int k = lane; k < K; k += 64) acc = fmaf(wp[k], ip[k], acc);
#pragma unroll
    for (int off = 32; off > 0; off >>= 1) acc += __shfl_xor(acc, off, 64);
    if (lane == 0) {
        float v = acc + bias[o];
        out[(size_t)b * N + o] = do_relu ? fmaxf(v, 0.f) : v;
    }
}

extern "C" void kernel_launch(void* const* d_in, const int* in_sizes, int n_in,
                              void* d_out, int out_size, void* d_ws, size_t ws_size,
                              hipStream_t stream) {
    const float* x          = (const float*)d_in[0];
    const float* enc_w      = (const float*)d_in[1];
    const float* enc_b      = (const float*)d_in[2];
    const float* log_dt     = (const float*)d_in[3];
    const float* C_re       = (const float*)d_in[4];
    const float* C_im       = (const float*)d_in[5];
    const float* log_A_real = (const float*)d_in[6];
    const float* A_imag     = (const float*)d_in[7];
    const float* Dp         = (const float*)d_in[8];
    const float* out_w      = (const float*)d_in[9];
    const float* out_b      = (const float*)d_in[10];
    const float* ln_w       = (const float*)d_in[11];
    const float* ln_b       = (const float*)d_in[12];
    const float* lin1_w     = (const float*)d_in[13];
    const float* lin1_b     = (const float*)d_in[14];
    const float* lin2_w     = (const float*)d_in[15];
    const float* lin2_b     = (const float*)d_in[16];
    const float* lin3_w     = (const float*)d_in[17];
    const float* lin3_b     = (const float*)d_in[18];
    float* outp = (float*)d_out;

    float* ws = (float*)d_ws;
    size_t off = 0;
    float* hbuf   = ws + off; off += (size_t)NB * LSEQ * NH;
    __hip_bfloat16* ybf = (__hip_bfloat16*)(ws + off); off += (size_t)NB * LSEQ * NH / 2;
    __hip_bfloat16* wbf = (__hip_bfloat16*)(ws + off); off += (size_t)NLAY * 2 * NH * NH / 2;
    float2* states = (float2*)(ws + off); off += (size_t)NB * NCH * NH * NN * 2;
    float* ctr    = ws + off; off += NLAY * NH * NN;
    float* cti    = ws + off; off += NLAY * NH * NN;
    float* er_    = ws + off; off += NLAY * NH * NN;
    float* ei_    = ws + off; off += NLAY * NH * NN;
    float* pr_    = ws + off; off += NLAY * NH * NN;
    float* pi_    = ws + off; off += NLAY * NH * NN;
    float* t1     = ws + off; off += NB * ML1;
    float* t2     = ws + off; off += NB * ML2;

    s4w_coef<<<(NLAY * NH * NN + 255) / 256, 256, 0, stream>>>(
        log_dt, C_re, C_im, log_A_real, A_imag, ctr, cti, er_, ei_, pr_, pi_);

    s4w_wprep<<<(NLAY * 2 * NH * NH) / 256, 256, 0, stream>>>(out_w, wbf);

    s4w_enc<<<NB * (LSEQ / 16), 256, 0, stream>>>(x, enc_w, enc_b, hbuf);

    for (int layer = 0; layer < NLAY; layer++) {
        s4w_convA<<<dim3(NB, NCH), 256, 0, stream>>>(hbuf, er_, ei_, states, layer);
        s4w_scan<<<(NB * NH * NN) / 256, 256, 0, stream>>>(states, pr_, pi_, layer);
        s4w_convC<<<dim3(NB, NCH), 256, 0, stream>>>(hbuf, ybf, states, er_, ei_, ctr, cti, Dp, layer);
        s4w_proj_mfma<<<dim3(NB, LSEQ / LTILE), 256, 0, stream>>>(ybf, hbuf, wbf, out_b, ln_w, ln_b, layer);
    }

    s4w_mlp_wave<<<(NB * ML1 + 3) / 4, 256, 0, stream>>>(
        hbuf + (size_t)(LSEQ - 1) * NH, (size_t)LSEQ * NH, lin1_w, lin1_b, t1, NH, ML1, 1);
    s4w_mlp_wave<<<(NB * ML2 + 3) / 4, 256, 0, stream>>>(
        t1, ML1, lin2_w, lin2_b, t2, ML1, ML2, 1);
    s4w_mlp_wave<<<(NB * MOUT + 3) / 4, 256, 0, stream>>>(
        t2, ML2, lin3_w, lin3_b, outp, ML2, MOUT, 0);
}

// Round 10
// 497.497 us; speedup vs baseline: 1.3809x; 1.3249x over previous
//
#include <hip/hip_runtime.h>
#include <hip/hip_bf16.h>
#include <math.h>

#define NB 32
#define LSEQ 2048
#define DIN 64
#define NH 256
#define NN 32
#define NLAY 2
#define NCH 32
#define TCH 64    // LSEQ/NCH
#define NBC (NB*NCH)          // 1024 columns
#define LTILE 64
#define ML1 350
#define ML2 400
#define MOUT 1024
#define LN_EPS 1e-5f

typedef short short8 __attribute__((ext_vector_type(8)));
typedef short short4v __attribute__((ext_vector_type(4)));
typedef float f32x4 __attribute__((ext_vector_type(4)));

__device__ __forceinline__ float bf2f(ushort u) {
    union { uint i; float f; } v; v.i = ((uint)u) << 16; return v.f;
}
__device__ __forceinline__ ushort f2bf(float f) {
    __hip_bfloat16 h = __float2bfloat16(f);
    return *reinterpret_cast<ushort*>(&h);
}

// ---------------- coefficient prep (E^64 for scan) ----------------
__global__ void s4w_coef(const float* __restrict__ log_dt,
                         const float* __restrict__ log_A_real, const float* __restrict__ A_imag,
                         float* __restrict__ pr_, float* __restrict__ pi_) {
    int idx = blockIdx.x * 256 + threadIdx.x;
    if (idx >= NLAY * NH * NN) return;
    int h = (idx / NN) % NH;
    int l = idx / (NN * NH);
    float dt = expf(log_dt[l * NH + h]);
    float ar = -expf(log_A_real[idx]);
    float ai = A_imag[idx];
    double dre = (double)(ar * dt), dim = (double)(ai * dt);
    double exT = exp(dre * (double)TCH);
    double ang = dim * (double)TCH;
    pr_[idx] = (float)(exT * cos(ang));
    pi_[idx] = (float)(exT * sin(ang));
}

// ---------------- matrix prep: Lmat (causal kernel), Wc (carry), Vmat (end-state) ----------------
// block = (layer*NH + h), 64 threads (t = row / lag index)
__global__ void s4w_matprep(const float* __restrict__ log_dt,
                            const float* __restrict__ C_re, const float* __restrict__ C_im,
                            const float* __restrict__ log_A_real, const float* __restrict__ A_imag,
                            ushort* __restrict__ Lmat, ushort* __restrict__ Wc,
                            ushort* __restrict__ Vmat) {
    int lh = blockIdx.x;          // layer*NH + h
    int t = threadIdx.x;          // 0..63
    __shared__ float ksh[64];
    float dt = expf(log_dt[lh]);
    float kacc = 0.f;
    for (int n = 0; n < NN; n++) {
        int idx = lh * NN + n;
        float ar = -expf(log_A_real[idx]);
        float ai = A_imag[idx];
        float dre = ar * dt, dim = ai * dt;
        // Ct = C * (exp(dtA)-1)/A, times 2 folded in
        float e1 = expf(dre);
        float er1 = e1 * cosf(dim), ei1 = e1 * sinf(dim);
        float den = ar * ar + ai * ai;
        float qr = ((er1 - 1.f) * ar + ei1 * ai) / den;
        float qi = (ei1 * ar - (er1 - 1.f) * ai) / den;
        float cr = C_re[idx], ci = C_im[idx];
        float ctr = 2.f * (cr * qr - ci * qi);
        float cti = 2.f * (cr * qi + ci * qr);
        // k_t = 2 Re(sum Ct E^t)
        float ed = expf(dre * (float)t);
        float angd = dim * (float)t;
        float erd = ed * cosf(angd), eid = ed * sinf(angd);
        kacc += ctr * erd - cti * eid;
        // Wc row t: w = Ct * E^(t+1);  [2n]=Re(w)*?  carry = sum Re(w)*sr - Im(w)*si
        float ew = expf(dre * (float)(t + 1));
        float angw = dim * (float)(t + 1);
        float ewr = ew * cosf(angw), ewi = ew * sinf(angw);
        float wr = ctr * ewr - cti * ewi;
        float wi = ctr * ewi + cti * ewr;
        Wc[(size_t)lh * 4096 + t * 64 + 2 * n]     = f2bf(wr);
        Wc[(size_t)lh * 4096 + t * 64 + 2 * n + 1] = f2bf(-wi);
        // Vmat column t: E^(63-t)  rows 2n (re), 2n+1 (im)
        float ev = expf(dre * (float)(63 - t));
        float angv = dim * (float)(63 - t);
        Vmat[(size_t)lh * 4096 + (2 * n) * 64 + t]     = f2bf(ev * cosf(angv));
        Vmat[(size_t)lh * 4096 + (2 * n + 1) * 64 + t] = f2bf(ev * sinf(angv));
    }
    ksh[t] = kacc;
    __syncthreads();
    for (int j = 0; j < 64; j++)
        Lmat[(size_t)lh * 4096 + t * 64 + j] = (j <= t) ? f2bf(ksh[t - j]) : (ushort)0;
}

// ---------------- weight prep: out_w -> bf16 ----------------
__global__ void s4w_wprep(const float* __restrict__ ow, ushort* __restrict__ wbf) {
    int idx = blockIdx.x * 256 + threadIdx.x;
    wbf[idx] = f2bf(ow[idx]);
}

// ---------------- encoder ----------------
__global__ void __launch_bounds__(256, 2)
s4w_enc(const float* __restrict__ x, const float* __restrict__ w,
        const float* __restrict__ bias, float* __restrict__ hbuf) {
    int blk = blockIdx.x;
    int b = blk / (LSEQ / 16);
    int l0 = (blk % (LSEQ / 16)) * 16;
    int t = threadIdx.x;
    __shared__ float xs[16][DIN];
    ((float4*)&xs[0][0])[t] = ((const float4*)(x + ((size_t)b * LSEQ + l0) * DIN))[t];
    float wr[DIN];
    const float4* wp4 = (const float4*)(w + (size_t)t * DIN);
#pragma unroll
    for (int i = 0; i < DIN / 4; i++) {
        float4 v = wp4[i];
        wr[4 * i] = v.x; wr[4 * i + 1] = v.y; wr[4 * i + 2] = v.z; wr[4 * i + 3] = v.w;
    }
    float bz = bias[t];
    __syncthreads();
#pragma unroll 4
    for (int l = 0; l < 16; l++) {
        float acc = bz;
#pragma unroll
        for (int i = 0; i < DIN; i++) acc = fmaf(wr[i], xs[l][i], acc);
        hbuf[((size_t)b * LSEQ + l0 + l) * NH + t] = acc;
    }
}

// ---------------- T1: hbuf f32 [b][l][h] -> u_t bf16 [h][bc][j] ----------------
__global__ void __launch_bounds__(256, 2)
s4w_t1(const float* __restrict__ hbuf, ushort* __restrict__ u_t) {
    int bc = blockIdx.x;              // b*32 + c
    int ht = blockIdx.y;              // 0..3
    int b = bc >> 5, c = bc & 31;
    int t = threadIdx.x;
    __shared__ float tile[64][65];    // [j][h']
    const float* src = hbuf + ((size_t)(b * LSEQ + c * 64)) * NH + ht * 64;
    int jr = t >> 4, h4 = t & 15;
#pragma unroll
    for (int p = 0; p < 4; p++) {
        int j = p * 16 + jr;
        float4 v = *(const float4*)(src + (size_t)j * NH + h4 * 4);
        tile[j][h4 * 4 + 0] = v.x; tile[j][h4 * 4 + 1] = v.y;
        tile[j][h4 * 4 + 2] = v.z; tile[j][h4 * 4 + 3] = v.w;
    }
    __syncthreads();
    int hr = t >> 2, jq = t & 3;
    ushort* dst = u_t + ((size_t)(ht * 64 + hr) * NBC + bc) * 64 + jq * 16;
    short8 o0, o1;
#pragma unroll
    for (int i = 0; i < 8; i++) {
        o0[i] = (short)f2bf(tile[jq * 16 + i][hr]);
        o1[i] = (short)f2bf(tile[jq * 16 + 8 + i][hr]);
    }
    *(short8*)dst = o0;
    *(short8*)(dst + 8) = o1;
}

// ---------------- gemmA: end-states = Vmat_h @ u_chunk  (per h) ----------------
__global__ void __launch_bounds__(256, 2)
s4w_gemmA(const ushort* __restrict__ u_t, const ushort* __restrict__ Vmat,
          ushort* __restrict__ statesbf, int layer) {
    int h = blockIdx.x, nt = blockIdx.y;
    int t = threadIdx.x, wave = t >> 6, lane = t & 63;
    int lm = lane & 15, kg = lane >> 4;
    int n0 = nt * 256 + wave * 64;
    const ushort* Ab = Vmat + (size_t)(layer * NH + h) * 4096;
    const ushort* Bb = u_t + (size_t)h * NBC * 64;
    f32x4 acc[4][4];
#pragma unroll
    for (int i = 0; i < 4; i++)
#pragma unroll
        for (int j = 0; j < 4; j++) acc[i][j] = (f32x4){0.f, 0.f, 0.f, 0.f};
#pragma unroll
    for (int ks = 0; ks < 2; ks++) {
        short8 av[4], bv[4];
#pragma unroll
        for (int mf = 0; mf < 4; mf++)
            av[mf] = *(const short8*)(Ab + (mf * 16 + lm) * 64 + ks * 32 + kg * 8);
#pragma unroll
        for (int nf = 0; nf < 4; nf++)
            bv[nf] = *(const short8*)(Bb + (size_t)(n0 + nf * 16 + lm) * 64 + ks * 32 + kg * 8);
#pragma unroll
        for (int mf = 0; mf < 4; mf++)
#pragma unroll
            for (int nf = 0; nf < 4; nf++)
                acc[mf][nf] = __builtin_amdgcn_mfma_f32_16x16x32_bf16(av[mf], bv[nf], acc[mf][nf], 0, 0, 0);
    }
#pragma unroll
    for (int mf = 0; mf < 4; mf++)
#pragma unroll
        for (int nf = 0; nf < 4; nf++) {
            int col = n0 + nf * 16 + lm;
            int row = mf * 16 + kg * 4;
            short4v pk;
#pragma unroll
            for (int j = 0; j < 4; j++) pk[j] = (short)f2bf(acc[mf][nf][j]);
            *(short4v*)(statesbf + ((size_t)h * NBC + col) * 64 + row) = pk;
        }
}

// ---------------- scan: end-states -> start-states (in place, bf16 io, f32 running) ----------------
__global__ void s4w_scan(ushort* __restrict__ statesbf,
                         const float* __restrict__ pr_, const float* __restrict__ pi_, int layer) {
    int idx = blockIdx.x * 256 + threadIdx.x;   // h*1024 + b*32 + n
    int n = idx & 31, b = (idx >> 5) & 31, h = idx >> 10;
    float pr = pr_[(size_t)(layer * NH + h) * NN + n];
    float pi = pi_[(size_t)(layer * NH + h) * NN + n];
    float sr = 0.f, si = 0.f;
    ushort* sp = statesbf + ((size_t)h * NBC + b * NCH) * 64 + 2 * n;
    for (int c = 0; c < NCH; c++) {
        uint v = *(const uint*)(sp + (size_t)c * 64);
        float er = bf2f((ushort)(v & 0xffff));
        float ei = bf2f((ushort)(v >> 16));
        *(uint*)(sp + (size_t)c * 64) = (uint)f2bf(sr) | ((uint)f2bf(si) << 16);
        float nsr = pr * sr - pi * si + er;
        float nsi = pr * si + pi * sr + ei;
        sr = nsr; si = nsi;
    }
}

// ---------------- gemmC: y = Lmat_h @ u + Wc_h @ s_start; + Dp*u; GELU; y overwrites u ----------------
__global__ void __launch_bounds__(256, 2)
s4w_gemmC(ushort* __restrict__ u_t, const ushort* __restrict__ statesbf,
          const ushort* __restrict__ Lmat, const ushort* __restrict__ Wc,
          const float* __restrict__ Dp, int layer) {
    int h = blockIdx.x, nt = blockIdx.y;
    int t = threadIdx.x, wave = t >> 6, lane = t & 63;
    int lm = lane & 15, kg = lane >> 4;
    int n0 = nt * 256 + wave * 64;
    const ushort* La = Lmat + (size_t)(layer * NH + h) * 4096;
    const ushort* Wa = Wc + (size_t)(layer * NH + h) * 4096;
    const ushort* Ub = u_t + (size_t)h * NBC * 64;
    const ushort* Sb = statesbf + (size_t)h * NBC * 64;
    f32x4 acc[4][4];
#pragma unroll
    for (int i = 0; i < 4; i++)
#pragma unroll
        for (int j = 0; j < 4; j++) acc[i][j] = (f32x4){0.f, 0.f, 0.f, 0.f};
    // phase 1: causal conv (A = Lmat, B = u)
#pragma unroll
    for (int ks = 0; ks < 2; ks++) {
        short8 av[4], bv[4];
#pragma unroll
        for (int mf = 0; mf < 4; mf++)
            av[mf] = *(const short8*)(La + (mf * 16 + lm) * 64 + ks * 32 + kg * 8);
#pragma unroll
        for (int nf = 0; nf < 4; nf++)
            bv[nf] = *(const short8*)(Ub + (size_t)(n0 + nf * 16 + lm) * 64 + ks * 32 + kg * 8);
#pragma unroll
        for (int mf = 0; mf < 4; mf++)
#pragma unroll
            for (int nf = 0; nf < 4; nf++)
                acc[mf][nf] = __builtin_amdgcn_mfma_f32_16x16x32_bf16(av[mf], bv[nf], acc[mf][nf], 0, 0, 0);
    }
    // phase 2: carry (A = Wc, B = start states)
#pragma unroll
    for (int ks = 0; ks < 2; ks++) {
        short8 av[4], bv[4];
#pragma unroll
        for (int mf = 0; mf < 4; mf++)
            av[mf] = *(const short8*)(Wa + (mf * 16 + lm) * 64 + ks * 32 + kg * 8);
#pragma unroll
        for (int nf = 0; nf < 4; nf++)
            bv[nf] = *(const short8*)(Sb + (size_t)(n0 + nf * 16 + lm) * 64 + ks * 32 + kg * 8);
#pragma unroll
        for (int mf = 0; mf < 4; mf++)
#pragma unroll
            for (int nf = 0; nf < 4; nf++)
                acc[mf][nf] = __builtin_amdgcn_mfma_f32_16x16x32_bf16(av[mf], bv[nf], acc[mf][nf], 0, 0, 0);
    }
    // epilogue: y = acc + Dp*u -> GELU -> bf16, in place over u
    float dp = Dp[layer * NH + h];
#pragma unroll
    for (int mf = 0; mf < 4; mf++)
#pragma unroll
        for (int nf = 0; nf < 4; nf++) {
            int col = n0 + nf * 16 + lm;
            int row = mf * 16 + kg * 4;
            ushort* base = u_t + ((size_t)h * NBC + col) * 64 + row;
            short4v uv = *(const short4v*)base;
            short4v yo;
#pragma unroll
            for (int j = 0; j < 4; j++) {
                float u = bf2f((ushort)uv[j]);
                float y = acc[mf][nf][j] + dp * u;
                float g = 0.5f * y * (1.0f + erff(y * 0.70710678118f));
                yo[j] = (short)f2bf(g);
            }
            *(short4v*)base = yo;
        }
}

// ---------------- T2: y_t bf16 [h][bc][j] -> ybf bf16 [b][l][h] ----------------
__global__ void __launch_bounds__(256, 2)
s4w_t2(const ushort* __restrict__ y_t, ushort* __restrict__ ybf) {
    int bc = blockIdx.x;
    int ht = blockIdx.y;
    int b = bc >> 5, c = bc & 31;
    int t = threadIdx.x;
    __shared__ ushort tile[64][65];   // [h'][j]
    int hr = t >> 2, jq = t & 3;
    const ushort* src = y_t + ((size_t)(ht * 64 + hr) * NBC + bc) * 64 + jq * 16;
    short8 i0 = *(const short8*)src;
    short8 i1 = *(const short8*)(src + 8);
#pragma unroll
    for (int i = 0; i < 8; i++) {
        tile[hr][jq * 16 + i] = (ushort)i0[i];
        tile[hr][jq * 16 + 8 + i] = (ushort)i1[i];
    }
    __syncthreads();
    int jr = t >> 2, hq = t & 3;
    ushort* dst = ybf + ((size_t)(b * LSEQ + c * 64 + jr)) * NH + ht * 64 + hq * 16;
    short8 o0, o1;
#pragma unroll
    for (int i = 0; i < 8; i++) {
        o0[i] = (short)tile[hq * 16 + i][jr];
        o1[i] = (short)tile[hq * 16 + 8 + i][jr];
    }
    *(short8*)dst = o0;
    *(short8*)(dst + 8) = o1;
}

// ---------------- proj: bf16 MFMA GEMM + GLU + residual + channel-LN ----------------
__global__ void __launch_bounds__(256, 2)
s4w_proj_mfma(const ushort* __restrict__ ybf, float* __restrict__ hbuf,
              const ushort* __restrict__ wbf, const float* __restrict__ ob,
              const float* __restrict__ lnw, const float* __restrict__ lnb, int layer) {
    int b = blockIdx.x;
    int n0 = blockIdx.y * LTILE;
    int t = threadIdx.x;
    int wave = t >> 6, lane = t & 63;
    int lm = lane & 15, kg = lane >> 4;

    __shared__ float glu[LTILE][NH + 1];
    __shared__ float ps[256], pq[256];
    __shared__ float mean_s[LTILE], rstd_s[LTILE];

    f32x4 acc[8][4];
#pragma unroll
    for (int i = 0; i < 8; i++)
#pragma unroll
        for (int j = 0; j < 4; j++) acc[i][j] = (f32x4){0.f, 0.f, 0.f, 0.f};

    const ushort* wp = wbf + (size_t)layer * 512 * NH;
    const ushort* yp = ybf + ((size_t)b * LSEQ + n0) * NH;

    const short8* aptr[8];
#pragma unroll
    for (int mi = 0; mi < 8; mi++) {
        int o = (mi < 4 ? wave * 64 + mi * 16 : 256 + wave * 64 + (mi - 4) * 16) + lm;
        aptr[mi] = (const short8*)(wp + (size_t)o * NH + kg * 8);
    }
    const short8* bptr[4];
#pragma unroll
    for (int ni = 0; ni < 4; ni++) {
        int l = ni * 16 + lm;
        bptr[ni] = (const short8*)(yp + (size_t)l * NH + kg * 8);
    }

#pragma unroll
    for (int ks = 0; ks < 8; ks++) {
        short8 bv[4], av[8];
#pragma unroll
        for (int ni = 0; ni < 4; ni++) bv[ni] = bptr[ni][ks * 4];
#pragma unroll
        for (int mi = 0; mi < 8; mi++) av[mi] = aptr[mi][ks * 4];
#pragma unroll
        for (int mi = 0; mi < 8; mi++)
#pragma unroll
            for (int ni = 0; ni < 4; ni++)
                acc[mi][ni] = __builtin_amdgcn_mfma_f32_16x16x32_bf16(av[mi], bv[ni], acc[mi][ni], 0, 0, 0);
    }

    float oba[4][4], obg[4][4];
#pragma unroll
    for (int mi = 0; mi < 4; mi++)
#pragma unroll
        for (int j = 0; j < 4; j++) {
            int o = wave * 64 + mi * 16 + kg * 4 + j;
            oba[mi][j] = ob[layer * 2 * NH + o];
            obg[mi][j] = ob[layer * 2 * NH + NH + o];
        }
#pragma unroll
    for (int mi = 0; mi < 4; mi++)
#pragma unroll
        for (int ni = 0; ni < 4; ni++)
#pragma unroll
            for (int j = 0; j < 4; j++) {
                float a = acc[mi][ni][j] + oba[mi][j];
                float g = acc[mi + 4][ni][j] + obg[mi][j];
                float v = a * (1.0f / (1.0f + expf(-g)));
                int o = wave * 64 + mi * 16 + kg * 4 + j;
                int l = ni * 16 + lm;
                glu[l][o] = v;
            }
    __syncthreads();

    const size_t hbase = ((size_t)b * LSEQ + n0) * NH;
    for (int l = 0; l < LTILE; l++)
        glu[l][t] += hbuf[hbase + (size_t)l * NH + t];
    __syncthreads();

    {
        int l = t & 63, seg = t >> 6;
        float s = 0.f, q = 0.f;
#pragma unroll
        for (int i = 0; i < 64; i++) {
            float v = glu[l][seg * 64 + i];
            s += v; q = fmaf(v, v, q);
        }
        ps[t] = s; pq[t] = q;
    }
    __syncthreads();
    if (t < 64) {
        float S = ps[t] + ps[64 + t] + ps[128 + t] + ps[192 + t];
        float Q = pq[t] + pq[64 + t] + pq[128 + t] + pq[192 + t];
        float m = S * (1.0f / NH);
        float v = Q * (1.0f / NH) - m * m;
        mean_s[t] = m; rstd_s[t] = rsqrtf(v + LN_EPS);
    }
    __syncthreads();

    float lw = lnw[layer * NH + t], lb = lnb[layer * NH + t];
    for (int l = 0; l < LTILE; l++) {
        float v = (glu[l][t] - mean_s[l]) * rstd_s[l] * lw + lb;
        hbuf[hbase + (size_t)l * NH + t] = v;
    }
}

// ---------------- head MLP: one wave per output element ----------------
__global__ void __launch_bounds__(256, 4)
s4w_mlp_wave(const float* __restrict__ in, size_t in_bstride,
             const float* __restrict__ w, const float* __restrict__ bias,
             float* __restrict__ out, int K, int N, int do_relu) {
    int wid = (blockIdx.x * 256 + threadIdx.x) >> 6;
    int lane = threadIdx.x & 63;
    if (wid >= NB * N) return;
    int b = wid / N, o = wid % N;
    const float* ip = in + (size_t)b * in_bstride;
    const float* wp = w + (size_t)o * K;
    float acc = 0.f;
    for (int k = lane; k < K; k += 64) acc = fmaf(wp[k], ip[k], acc);
#pragma unroll
    for (int off = 32; off > 0; off >>= 1) acc += __shfl_xor(acc, off, 64);
    if (lane == 0) {
        float v = acc + bias[o];
        out[(size_t)b * N + o] = do_relu ? fmaxf(v, 0.f) : v;
    }
}

extern "C" void kernel_launch(void* const* d_in, const int* in_sizes, int n_in,
                              void* d_out, int out_size, void* d_ws, size_t ws_size,
                              hipStream_t stream) {
    const float* x          = (const float*)d_in[0];
    const float* enc_w      = (const float*)d_in[1];
    const float* enc_b      = (const float*)d_in[2];
    const float* log_dt     = (const float*)d_in[3];
    const float* C_re       = (const float*)d_in[4];
    const float* C_im       = (const float*)d_in[5];
    const float* log_A_real = (const float*)d_in[6];
    const float* A_imag     = (const float*)d_in[7];
    const float* Dp         = (const float*)d_in[8];
    const float* out_w      = (const float*)d_in[9];
    const float* out_b      = (const float*)d_in[10];
    const float* ln_w       = (const float*)d_in[11];
    const float* ln_b       = (const float*)d_in[12];
    const float* lin1_w     = (const float*)d_in[13];
    const float* lin1_b     = (const float*)d_in[14];
    const float* lin2_w     = (const float*)d_in[15];
    const float* lin2_b     = (const float*)d_in[16];
    const float* lin3_w     = (const float*)d_in[17];
    const float* lin3_b     = (const float*)d_in[18];
    float* outp = (float*)d_out;

    float* ws = (float*)d_ws;
    size_t off = 0;
    float* hbuf = ws + off;              off += (size_t)NB * LSEQ * NH;            // 16.78M f32
    ushort* u_t = (ushort*)(ws + off);   off += (size_t)NH * NBC * 64 / 2;         // 16.78M bf16 (u / y in place)
    ushort* statesbf = (ushort*)(ws + off); off += (size_t)NH * NBC * 64 / 2;      // states; aliased as ybf
    ushort* wbf = (ushort*)(ws + off);   off += (size_t)NLAY * 2 * NH * NH / 2;
    ushort* Lmat = (ushort*)(ws + off);  off += (size_t)NLAY * NH * 4096 / 2;
    ushort* Wc   = (ushort*)(ws + off);  off += (size_t)NLAY * NH * 4096 / 2;
    ushort* Vmat = (ushort*)(ws + off);  off += (size_t)NLAY * NH * 4096 / 2;
    float* pr_ = ws + off;               off += NLAY * NH * NN;
    float* pi_ = ws + off;               off += NLAY * NH * NN;
    float* t1  = ws + off;               off += NB * ML1;
    float* t2  = ws + off;               off += NB * ML2;
    ushort* ybf = statesbf;   // reuse: states consumed by gemmC before T2 writes ybf

    s4w_coef<<<(NLAY * NH * NN + 255) / 256, 256, 0, stream>>>(
        log_dt, log_A_real, A_imag, pr_, pi_);
    s4w_matprep<<<NLAY * NH, 64, 0, stream>>>(
        log_dt, C_re, C_im, log_A_real, A_imag, Lmat, Wc, Vmat);
    s4w_wprep<<<(NLAY * 2 * NH * NH) / 256, 256, 0, stream>>>(out_w, wbf);

    s4w_enc<<<NB * (LSEQ / 16), 256, 0, stream>>>(x, enc_w, enc_b, hbuf);

    for (int layer = 0; layer < NLAY; layer++) {
        s4w_t1<<<dim3(NBC, 4), 256, 0, stream>>>(hbuf, u_t);
        s4w_gemmA<<<dim3(NH, 4), 256, 0, stream>>>(u_t, Vmat, statesbf, layer);
        s4w_scan<<<(NH * NB * NN) / 256, 256, 0, stream>>>(statesbf, pr_, pi_, layer);
        s4w_gemmC<<<dim3(NH, 4), 256, 0, stream>>>(u_t, statesbf, Lmat, Wc, Dp, layer);
        s4w_t2<<<dim3(NBC, 4), 256, 0, stream>>>(u_t, ybf);
        s4w_proj_mfma<<<dim3(NB, LSEQ / LTILE), 256, 0, stream>>>(ybf, hbuf, wbf, out_b, ln_w, ln_b, layer);
    }

    s4w_mlp_wave<<<(NB * ML1 + 3) / 4, 256, 0, stream>>>(
        hbuf + (size_t)(LSEQ - 1) * NH, (size_t)LSEQ * NH, lin1_w, lin1_b, t1, NH, ML1, 1);
    s4w_mlp_wave<<<(NB * ML2 + 3) / 4, 256, 0, stream>>>(
        t1, ML1, lin2_w, lin2_b, t2, ML1, ML2, 1);
    s4w_mlp_wave<<<(NB * MOUT + 3) / 4, 256, 0, stream>>>(
        t2, ML2, lin3_w, lin3_b, outp, ML2, MOUT, 0);
}